// Round 1
// baseline (337.737 us; speedup 1.0000x reference)
//
#include <hip/hip_runtime.h>
#include <math.h>
#include <float.h>

#define TAU 0.95f
#define PEN 0.2f
#define NT 256
#define KMAX 8

__global__ __launch_bounds__(NT) void saps_kernel(
    const float* __restrict__ logits, const float* __restrict__ u,
    float* __restrict__ out_cumsum, float* __restrict__ out_sizes,
    float* __restrict__ out_mask, int C)
{
    const int row = blockIdx.x;
    const int tid = threadIdx.x;
    const float* __restrict__ x = logits + (size_t)row * C;

    __shared__ float s_val[NT];
    __shared__ int   s_idx[NT];
    __shared__ int   sel[KMAX];

    // ---- pass 1: max + first-argmax (tie -> smaller index) ----
    float bm = -FLT_MAX; int bi = 0x7fffffff;
    for (int j = tid; j < C; j += NT) {
        float v = x[j];
        if (v > bm) { bm = v; bi = j; }   // strictly greater keeps first index within stride
    }
    s_val[tid] = bm; s_idx[tid] = bi;
    __syncthreads();
    for (int off = NT / 2; off > 0; off >>= 1) {
        if (tid < off) {
            float v2 = s_val[tid + off]; int i2 = s_idx[tid + off];
            if (v2 > s_val[tid] || (v2 == s_val[tid] && i2 < s_idx[tid])) {
                s_val[tid] = v2; s_idx[tid] = i2;
            }
        }
        __syncthreads();
    }
    const float m    = s_val[0];
    const int   amax = s_idx[0];
    __syncthreads();

    // ---- pass 2: sum of exp(x - m) ----
    float ps = 0.0f;
    for (int j = tid; j < C; j += NT) ps += expf(x[j] - m);
    s_val[tid] = ps;
    __syncthreads();
    for (int off = NT / 2; off > 0; off >>= 1) {
        if (tid < off) s_val[tid] += s_val[tid + off];
        __syncthreads();
    }
    const float sum  = s_val[0];
    __syncthreads();
    const float pmax = 1.0f / sum;   // probs[argmax] = exp(0)/sum

    // ---- sequential f32 cumsum prefix: ordered = [pmax, 0.2, 0.2, ...] ----
    float cs[KMAX];
    cs[0] = pmax;
    #pragma unroll
    for (int j = 1; j < KMAX; j++) cs[j] = cs[j - 1] + PEN;

    int cnt = 0;
    #pragma unroll
    for (int j = 0; j < KMAX; j++) if (cs[j] <= TAU) cnt++;   // monotone; cnt <= 5 since cs[5] >= 1.0
    int sizes_base = cnt + 1;
    if (sizes_base > C) sizes_base = C;

    int k = sizes_base - 1;
    if (k >= KMAX) k = KMAX - 1;                // safety, unreachable with pmax >= 1/C
    const float o_k = (k == 0) ? cs[0] : PEN;
    const float c_k = cs[k];
    const float V = (TAU - (c_k - o_k)) / o_k;
    int sz = sizes_base - ((u[row] >= V) ? 1 : 0);
    if (sz > KMAX) sz = KMAX;                   // safety
    if (sz < 0) sz = 0;

    // ---- top-sz selection (rank by logit desc, index asc). rank 0 = argmax ----
    if (tid == 0) sel[0] = amax;
    __syncthreads();
    for (int t = 1; t < sz; t++) {
        float bm2 = -FLT_MAX; int bi2 = 0x7fffffff;
        for (int j = tid; j < C; j += NT) {
            bool skip = false;
            #pragma unroll
            for (int q = 0; q < KMAX; q++) skip |= (q < t) && (sel[q] == j);
            if (skip) continue;
            float v = x[j];
            if (v > bm2) { bm2 = v; bi2 = j; }
        }
        s_val[tid] = bm2; s_idx[tid] = bi2;
        __syncthreads();
        for (int off = NT / 2; off > 0; off >>= 1) {
            if (tid < off) {
                float v2 = s_val[tid + off]; int i2 = s_idx[tid + off];
                if (v2 > s_val[tid] || (v2 == s_val[tid] && i2 < s_idx[tid])) {
                    s_val[tid] = v2; s_idx[tid] = i2;
                }
            }
            __syncthreads();
        }
        if (tid == 0) sel[t] = s_idx[0];
        __syncthreads();
    }

    // ---- write cumsum, mask, sizes ----
    float* __restrict__ oc = out_cumsum + (size_t)row * C;
    float* __restrict__ om = out_mask   + (size_t)row * C;
    for (int j = tid; j < C; j += NT) {
        float cv = (j < KMAX) ? cs[j] : (pmax + PEN * (float)j);
        oc[j] = cv;
        bool in = false;
        #pragma unroll
        for (int q = 0; q < KMAX; q++) in |= (q < sz) && (sel[q] == j);
        om[j] = in ? 1.0f : 0.0f;
    }
    if (tid == 0) out_sizes[row] = (float)sz;
}

extern "C" void kernel_launch(void* const* d_in, const int* in_sizes, int n_in,
                              void* d_out, int out_size, void* d_ws, size_t ws_size,
                              hipStream_t stream) {
    const float* logits = (const float*)d_in[0];
    const float* u      = (const float*)d_in[1];
    const int B = in_sizes[1];
    const int C = in_sizes[0] / B;

    float* out        = (float*)d_out;
    float* out_cumsum = out;                         // B*C
    float* out_sizes  = out + (size_t)B * C;         // B
    float* out_mask   = out + (size_t)B * C + B;     // B*C

    saps_kernel<<<dim3(B), dim3(NT), 0, stream>>>(logits, u, out_cumsum, out_sizes, out_mask, C);
}

// Round 2
// 143.832 us; speedup vs baseline: 2.3481x; 2.3481x over previous
//
#include <hip/hip_runtime.h>
#include <math.h>
#include <float.h>

#define TAU 0.95f
#define PEN 0.2f
#define NT 256
#define KSEL 6
#define KMAX 8

__global__ __launch_bounds__(NT) void saps_kernel(
    const float* __restrict__ logits, const float* __restrict__ u,
    float* __restrict__ out_cumsum, float* __restrict__ out_sizes,
    float* __restrict__ out_mask, int C)
{
    const int row = blockIdx.x;
    const int tid = threadIdx.x;
    const float* __restrict__ x = logits + (size_t)row * C;

    __shared__ float s_m[NT];
    __shared__ float s_s[NT];
    __shared__ float s_cv[NT * KSEL];
    __shared__ int   s_ci[NT * KSEL];
    __shared__ float s_rv[NT];
    __shared__ int   s_ri[NT];
    __shared__ int   s_sel[KSEL];

    // ---- single streaming pass: online softmax + per-thread top-6 ----
    float m_loc = -FLT_MAX;
    float s_loc = 0.0f;
    float tv[KSEL];
    int   ti[KSEL];
    #pragma unroll
    for (int q = 0; q < KSEL; q++) { tv[q] = -FLT_MAX; ti[q] = 0x7fffffff; }

    auto proc = [&](float v, int j) {
        // online softmax (rescale on new max; rare branch)
        if (v > m_loc) {
            s_loc = s_loc * __expf(m_loc - v) + 1.0f;
            m_loc = v;
        } else {
            s_loc += __expf(v - m_loc);
        }
        // top-6 (strict > keeps earliest index on ties; indices ascend in-thread)
        if (v > tv[KSEL - 1]) {
            tv[KSEL - 1] = v; ti[KSEL - 1] = j;
            #pragma unroll
            for (int q = KSEL - 1; q > 0; --q) {
                if (tv[q] > tv[q - 1]) {
                    float fv = tv[q]; tv[q] = tv[q - 1]; tv[q - 1] = fv;
                    int   fi = ti[q]; ti[q] = ti[q - 1]; ti[q - 1] = fi;
                }
            }
        }
    };

    const int C4 = C >> 2;
    const bool vec_ok = ((C & 3) == 0) && ((((size_t)x) & 15) == 0);
    if (vec_ok) {
        const float4* __restrict__ x4 = (const float4*)x;
        for (int q = tid; q < C4; q += NT) {
            float4 v = x4[q];
            int j = q << 2;
            proc(v.x, j); proc(v.y, j + 1); proc(v.z, j + 2); proc(v.w, j + 3);
        }
    } else {
        for (int j = tid; j < C; j += NT) proc(x[j], j);
    }

    // ---- reduce (m, s) across threads ----
    s_m[tid] = m_loc; s_s[tid] = s_loc;
    __syncthreads();
    for (int off = NT / 2; off > 0; off >>= 1) {
        if (tid < off) {
            float m1 = s_m[tid], s1 = s_s[tid];
            float m2 = s_m[tid + off], s2 = s_s[tid + off];
            float mm = fmaxf(m1, m2);
            s_s[tid] = s1 * __expf(m1 - mm) + s2 * __expf(m2 - mm);
            s_m[tid] = mm;
        }
        __syncthreads();
    }
    const float pmax = 1.0f / s_s[0];
    __syncthreads();

    // ---- dump per-thread candidates to LDS ----
    #pragma unroll
    for (int q = 0; q < KSEL; q++) {
        s_cv[tid * KSEL + q] = tv[q];
        s_ci[tid * KSEL + q] = ti[q];
    }

    // ---- sizes (same logic as passing R1 kernel) ----
    float cs[KMAX];
    cs[0] = pmax;
    #pragma unroll
    for (int j = 1; j < KMAX; j++) cs[j] = cs[j - 1] + PEN;
    int cnt = 0;
    #pragma unroll
    for (int j = 0; j < KMAX; j++) if (cs[j] <= TAU) cnt++;
    int sizes_base = cnt + 1;
    if (sizes_base > C) sizes_base = C;
    int k = sizes_base - 1;
    if (k >= KMAX) k = KMAX - 1;
    const float o_k = (k == 0) ? cs[0] : PEN;
    const float c_k = cs[k];
    const float V = (TAU - (c_k - o_k)) / o_k;
    int sz = sizes_base - ((u[row] >= V) ? 1 : 0);
    if (sz > KSEL) sz = KSEL;
    if (sz < 0) sz = 0;

    __syncthreads();

    // ---- select top-sz from the 256*6 candidates ----
    for (int r = 0; r < sz; ++r) {
        float bv = -FLT_MAX; int bi = 0x7fffffff;
        #pragma unroll
        for (int q = 0; q < KSEL; ++q) {
            float v = s_cv[tid * KSEL + q];
            int  jj = s_ci[tid * KSEL + q];
            bool excl = false;
            for (int e = 0; e < r; ++e) excl |= (s_sel[e] == jj);
            if (!excl && (v > bv || (v == bv && jj < bi))) { bv = v; bi = jj; }
        }
        s_rv[tid] = bv; s_ri[tid] = bi;
        __syncthreads();
        for (int off = NT / 2; off > 0; off >>= 1) {
            if (tid < off) {
                float v2 = s_rv[tid + off]; int i2 = s_ri[tid + off];
                if (v2 > s_rv[tid] || (v2 == s_rv[tid] && i2 < s_ri[tid])) {
                    s_rv[tid] = v2; s_ri[tid] = i2;
                }
            }
            __syncthreads();
        }
        if (tid == 0) s_sel[r] = s_ri[0];
        __syncthreads();
    }

    // ---- write cumsum (analytic) + zero mask, then scatter ones ----
    float* __restrict__ oc = out_cumsum + (size_t)row * C;
    float* __restrict__ om = out_mask   + (size_t)row * C;
    if (vec_ok && ((((size_t)oc) & 15) == 0) && ((((size_t)om) & 15) == 0)) {
        float4* __restrict__ oc4 = (float4*)oc;
        float4* __restrict__ om4 = (float4*)om;
        const float4 z4 = make_float4(0.f, 0.f, 0.f, 0.f);
        for (int q = tid; q < C4; q += NT) {
            float j0 = (float)(q << 2);
            float4 cv;
            cv.x = fmaf(PEN, j0,        pmax);
            cv.y = fmaf(PEN, j0 + 1.0f, pmax);
            cv.z = fmaf(PEN, j0 + 2.0f, pmax);
            cv.w = fmaf(PEN, j0 + 3.0f, pmax);
            oc4[q] = cv;
            om4[q] = z4;
        }
    } else {
        for (int j = tid; j < C; j += NT) {
            oc[j] = fmaf(PEN, (float)j, pmax);
            om[j] = 0.0f;
        }
    }
    __syncthreads();
    if (tid < sz) om[s_sel[tid]] = 1.0f;
    if (tid == 0) out_sizes[row] = (float)sz;
}

extern "C" void kernel_launch(void* const* d_in, const int* in_sizes, int n_in,
                              void* d_out, int out_size, void* d_ws, size_t ws_size,
                              hipStream_t stream) {
    const float* logits = (const float*)d_in[0];
    const float* u      = (const float*)d_in[1];
    const int B = in_sizes[1];
    const int C = in_sizes[0] / B;

    float* out        = (float*)d_out;
    float* out_cumsum = out;                         // B*C
    float* out_sizes  = out + (size_t)B * C;         // B
    float* out_mask   = out + (size_t)B * C + B;     // B*C

    saps_kernel<<<dim3(B), dim3(NT), 0, stream>>>(logits, u, out_cumsum, out_sizes, out_mask, C);
}

// Round 4
// 89.782 us; speedup vs baseline: 3.7617x; 1.6020x over previous
//
#include <hip/hip_runtime.h>
#include <math.h>
#include <float.h>

#define TAU 0.95f
#define PEN 0.2f
#define NT 256
#define NW (NT / 64)
#define KSEL 6
#define KMAX 8

typedef float f32x4 __attribute__((ext_vector_type(4)));

__device__ __forceinline__ void amax2(float& bv, int& bi, float ov, int oi) {
    if (ov > bv || (ov == bv && oi < bi)) { bv = ov; bi = oi; }
}

__global__ __launch_bounds__(NT) void saps_kernel(
    const float* __restrict__ logits, const float* __restrict__ u,
    float* __restrict__ out_cumsum, float* __restrict__ out_sizes,
    float* __restrict__ out_mask, int C)
{
    const int row  = blockIdx.x;
    const int tid  = threadIdx.x;
    const int lane = tid & 63;
    const int wv   = tid >> 6;
    const float* __restrict__ x = logits + (size_t)row * C;

    __shared__ float s_m[NW], s_s[NW];
    __shared__ float s_cv[NW * KSEL];
    __shared__ int   s_ci[NW * KSEL];
    __shared__ int   s_sel[KSEL];
    __shared__ float s_sz;

    // ---- single streaming pass: branchless online softmax + per-thread top-6 ----
    float m_loc = -FLT_MAX, s_loc = 0.0f;
    float tv[KSEL]; int ti[KSEL];
    #pragma unroll
    for (int q = 0; q < KSEL; q++) { tv[q] = -FLT_MAX; ti[q] = 0x7fffffff; }

    auto proc = [&](float v, int j) {
        float nm = fmaxf(m_loc, v);
        s_loc = fmaf(s_loc, __expf(m_loc - nm), __expf(v - nm));
        m_loc = nm;
        if (v > tv[KSEL - 1]) {           // indices ascend per thread; strict > keeps earliest on tie
            tv[KSEL - 1] = v; ti[KSEL - 1] = j;
            #pragma unroll
            for (int q = KSEL - 1; q > 0; --q) {
                if (tv[q] > tv[q - 1]) {
                    float fv = tv[q]; tv[q] = tv[q - 1]; tv[q - 1] = fv;
                    int   fi = ti[q]; ti[q] = ti[q - 1]; ti[q - 1] = fi;
                }
            }
        }
    };

    const int C4 = C >> 2;
    const bool vec_ok = ((C & 3) == 0);
    if (vec_ok) {
        const f32x4* __restrict__ x4 = (const f32x4*)x;
        for (int q = tid; q < C4; q += NT) {
            f32x4 v = x4[q];
            int j = q << 2;
            proc(v.x, j); proc(v.y, j + 1); proc(v.z, j + 2); proc(v.w, j + 3);
        }
    } else {
        for (int j = tid; j < C; j += NT) proc(x[j], j);
    }

    // ---- wave-level (m,s) reduce via shfl ----
    #pragma unroll
    for (int off = 32; off > 0; off >>= 1) {
        float om2 = __shfl_xor(m_loc, off);
        float os2 = __shfl_xor(s_loc, off);
        float nm = fmaxf(m_loc, om2);
        s_loc = s_loc * __expf(m_loc - nm) + os2 * __expf(om2 - nm);
        m_loc = nm;
    }
    if (lane == 0) { s_m[wv] = m_loc; s_s[wv] = s_loc; }

    // ---- per-wave sorted top-6 via 6 shfl-argmax rounds (register kill) ----
    #pragma unroll
    for (int r = 0; r < KSEL; r++) {
        float bv = -FLT_MAX; int bi = 0x7fffffff;
        #pragma unroll
        for (int q = 0; q < KSEL; q++) amax2(bv, bi, tv[q], ti[q]);
        #pragma unroll
        for (int off = 32; off > 0; off >>= 1) {
            float ov = __shfl_xor(bv, off);
            int   oi = __shfl_xor(bi, off);
            amax2(bv, bi, ov, oi);
        }
        if (lane == 0) { s_cv[wv * KSEL + r] = bv; s_ci[wv * KSEL + r] = bi; }
        #pragma unroll
        for (int q = 0; q < KSEL; q++)
            if (ti[q] == bi) { tv[q] = -FLT_MAX; ti[q] = 0x7fffffff; }
    }
    __syncthreads();

    // ---- all threads: combine 4 wave partials -> pmax ----
    float mm = s_m[0], ss = s_s[0];
    #pragma unroll
    for (int w2 = 1; w2 < NW; w2++) {
        float m2 = s_m[w2], s2 = s_s[w2];
        float nm = fmaxf(mm, m2);
        ss = ss * __expf(mm - nm) + s2 * __expf(m2 - nm);
        mm = nm;
    }
    const float pmax = 1.0f / ss;

    // ---- wave 0: sizes + cross-wave top-6 merge ----
    if (wv == 0) {
        float cs[KMAX];
        cs[0] = pmax;
        #pragma unroll
        for (int j = 1; j < KMAX; j++) cs[j] = cs[j - 1] + PEN;
        int cnt = 0;
        #pragma unroll
        for (int j = 0; j < KMAX; j++) if (cs[j] <= TAU) cnt++;
        int sizes_base = cnt + 1;
        if (sizes_base > C) sizes_base = C;
        int k = sizes_base - 1;
        if (k >= KMAX) k = KMAX - 1;
        const float o_k = (k == 0) ? cs[0] : PEN;
        const float c_k = cs[k];
        const float V = (TAU - (c_k - o_k)) / o_k;
        int sz = sizes_base - ((u[row] >= V) ? 1 : 0);
        if (sz > KSEL) sz = KSEL;
        if (sz < 0) sz = 0;

        float cv2 = -FLT_MAX; int ci2 = 0x7fffffff;
        if (lane < NW * KSEL) { cv2 = s_cv[lane]; ci2 = s_ci[lane]; }
        #pragma unroll
        for (int r = 0; r < KSEL; r++) {
            float bv = cv2; int bi = ci2;
            #pragma unroll
            for (int off = 32; off > 0; off >>= 1) {
                float ov = __shfl_xor(bv, off);
                int   oi = __shfl_xor(bi, off);
                amax2(bv, bi, ov, oi);
            }
            if (lane == 0) s_sel[r] = (r < sz) ? bi : -1;
            if (ci2 == bi) { cv2 = -FLT_MAX; ci2 = 0x7fffffff; }
        }
        if (lane == 0) s_sz = (float)sz;
    }
    __syncthreads();

    const int s0 = s_sel[0], s1 = s_sel[1], s2i = s_sel[2];
    const int s3 = s_sel[3], s4 = s_sel[4], s5 = s_sel[5];

    // ---- single write pass: analytic cumsum + inline membership mask ----
    float* __restrict__ oc = out_cumsum + (size_t)row * C;
    float* __restrict__ om = out_mask   + (size_t)row * C;
    if (vec_ok) {
        f32x4* __restrict__ oc4 = (f32x4*)oc;
        f32x4* __restrict__ om4 = (f32x4*)om;
        for (int q = tid; q < C4; q += NT) {
            const int j0 = q << 2;
            f32x4 cv;
            cv.x = fmaf(PEN, (float)(j0),     pmax);
            cv.y = fmaf(PEN, (float)(j0 + 1), pmax);
            cv.z = fmaf(PEN, (float)(j0 + 2), pmax);
            cv.w = fmaf(PEN, (float)(j0 + 3), pmax);
            f32x4 mv;
            mv.x = (j0     == s0 || j0     == s1 || j0     == s2i || j0     == s3 || j0     == s4 || j0     == s5) ? 1.0f : 0.0f;
            mv.y = (j0 + 1 == s0 || j0 + 1 == s1 || j0 + 1 == s2i || j0 + 1 == s3 || j0 + 1 == s4 || j0 + 1 == s5) ? 1.0f : 0.0f;
            mv.z = (j0 + 2 == s0 || j0 + 2 == s1 || j0 + 2 == s2i || j0 + 2 == s3 || j0 + 2 == s4 || j0 + 2 == s5) ? 1.0f : 0.0f;
            mv.w = (j0 + 3 == s0 || j0 + 3 == s1 || j0 + 3 == s2i || j0 + 3 == s3 || j0 + 3 == s4 || j0 + 3 == s5) ? 1.0f : 0.0f;
            __builtin_nontemporal_store(cv, oc4 + q);
            __builtin_nontemporal_store(mv, om4 + q);
        }
    } else {
        for (int j = tid; j < C; j += NT) {
            oc[j] = fmaf(PEN, (float)j, pmax);
            om[j] = (j == s0 || j == s1 || j == s2i || j == s3 || j == s4 || j == s5) ? 1.0f : 0.0f;
        }
    }
    if (tid == 0) out_sizes[row] = s_sz;
}

extern "C" void kernel_launch(void* const* d_in, const int* in_sizes, int n_in,
                              void* d_out, int out_size, void* d_ws, size_t ws_size,
                              hipStream_t stream) {
    const float* logits = (const float*)d_in[0];
    const float* u      = (const float*)d_in[1];
    const int B = in_sizes[1];
    const int C = in_sizes[0] / B;

    float* out        = (float*)d_out;
    float* out_cumsum = out;                         // B*C
    float* out_sizes  = out + (size_t)B * C;         // B
    float* out_mask   = out + (size_t)B * C + B;     // B*C

    saps_kernel<<<dim3(B), dim3(NT), 0, stream>>>(logits, u, out_cumsum, out_sizes, out_mask, C);
}